// Round 6
// baseline (173.542 us; speedup 1.0000x reference)
//
#include <hip/hip_runtime.h>

#define NEG_INF (-1e30f)

typedef __bf16 bf16x8 __attribute__((ext_vector_type(8)));
typedef float  f32x4  __attribute__((ext_vector_type(4)));
typedef unsigned short ushort;

__device__ __forceinline__ float fast_tanhf(float x) {
    // 1 - 2*rcp(1+e^{2x}) : v_exp + v_rcp, no IEEE divide (~6 VALU ops)
    float e = __expf(2.0f * x);
    return 1.0f - 2.0f * __builtin_amdgcn_rcpf(1.0f + e);
}

__device__ __forceinline__ ushort f2bf(float f) {
    union { float f; unsigned u; } v; v.f = f;
    unsigned r = v.u + 0x7fffu + ((v.u >> 16) & 1u);   // RNE
    return (ushort)(r >> 16);
}

// async global->LDS, 16B/lane, LDS dest = wave-uniform base + lane*16
__device__ __forceinline__ void gload_lds16(const void* gsrc, void* ldsdst) {
    __builtin_amdgcn_global_load_lds(
        (const __attribute__((address_space(1))) unsigned int*)gsrc,
        (__attribute__((address_space(3))) unsigned int*)ldsdst, 16, 0, 0);
}

// ---------------------------------------------------------------------------
// K0: W_sa [H=512][C=512] fp32 -> Wt [C][H] bf16 (transposed)
// ---------------------------------------------------------------------------
__global__ void convw_kernel(const float* __restrict__ W, ushort* __restrict__ Wt) {
    int i = blockIdx.x * 256 + threadIdx.x;
    int h = i >> 9, c = i & 511;
    Wt[c * 512 + h] = f2bf(W[i]);
}

// ---------------------------------------------------------------------------
// K1: 128x128-tile GEMM, m97-style SINGLE-buffer 2-barrier loop, blocked LDS,
// XCD-aware flat grid, fused tanh*w_sc row-reduce epilogue.
// Occupancy is the lever: LDS 17KB, VGPR-capped 5 blocks/CU (launch_bounds).
// LDS tile layout (A and B): ushort idx = (r>>4)*512 + kseg*128 + (r&15)*8
// -> every ds_read_b128 is 16 lanes x 256 contiguous bytes (2-way, free).
// ---------------------------------------------------------------------------
__global__ __launch_bounds__(256, 5) void gemm_scores_kernel(
    const float* __restrict__ feat, const ushort* __restrict__ Wt,
    const float* __restrict__ b_sa, const float* __restrict__ w_sc,
    float* __restrict__ sp) {

    __shared__ ushort Alds[4096];
    __shared__ ushort Blds[4096];
    __shared__ float  redE[4][64];

    const int tid  = threadIdx.x;
    const int id   = blockIdx.x;
    const int g    = id & 7;                 // XCD (round-robin dispatch)
    const int c8   = id >> 3;                // 0..255
    const int my   = g * 64 + (c8 >> 2);     // M-panel 0..511
    const int by   = c8 & 3;                 // N-chunk 0..3
    const int m0   = my * 128;
    const int n0   = by * 128;

    const int lane = tid & 63;
    const int wv   = tid >> 6;
    const int wm   = wv >> 1, wn = wv & 1;   // 2M x 2N wave grid (64x64 each)
    const int lr   = lane & 15;
    const int kg   = lane >> 4;

    const int arow = tid >> 1;               // 0..127
    const int aseg = (tid & 1) * 16;         // 0 or 16 (floats)
    const float* agp = feat + (size_t)(m0 + arow) * 512 + aseg;
    const int wA = (arow >> 4) * 512 + (aseg >> 3) * 128 + (arow & 15) * 8;

    const ushort* bg0 = Wt + (size_t)(n0 + (0 * 4 + wv) * 16 + lr) * 512 + kg * 8;
    const ushort* bg1 = Wt + (size_t)(n0 + (1 * 4 + wv) * 16 + lr) * 512 + kg * 8;

    const int aBase = wm * 2048 + kg * 128 + lr * 8;
    const int bBase = wn * 2048 + kg * 128 + lr * 8;

    f32x4 acc[4][4];
#pragma unroll
    for (int a = 0; a < 4; ++a)
#pragma unroll
        for (int b = 0; b < 4; ++b) acc[a][b] = (f32x4){0.f, 0.f, 0.f, 0.f};

    // A(0) into regs
    float4 p0 = *reinterpret_cast<const float4*>(agp + 0);
    float4 p1 = *reinterpret_cast<const float4*>(agp + 4);
    float4 p2 = *reinterpret_cast<const float4*>(agp + 8);
    float4 p3 = *reinterpret_cast<const float4*>(agp + 12);

    for (int k0 = 0; k0 < 512; k0 += 32) {
        // ---- stage phase: glds B(t) + cvt/ds_write A(t) ----
        gload_lds16(bg0 + k0, (char*)Blds + wv * 1024);
        gload_lds16(bg1 + k0, (char*)Blds + 4096 + wv * 1024);
        {
            bf16x8 h0, h1;
            h0[0] = (__bf16)p0.x; h0[1] = (__bf16)p0.y; h0[2] = (__bf16)p0.z; h0[3] = (__bf16)p0.w;
            h0[4] = (__bf16)p1.x; h0[5] = (__bf16)p1.y; h0[6] = (__bf16)p1.z; h0[7] = (__bf16)p1.w;
            h1[0] = (__bf16)p2.x; h1[1] = (__bf16)p2.y; h1[2] = (__bf16)p2.z; h1[3] = (__bf16)p2.w;
            h1[4] = (__bf16)p3.x; h1[5] = (__bf16)p3.y; h1[6] = (__bf16)p3.z; h1[7] = (__bf16)p3.w;
            *reinterpret_cast<bf16x8*>(&Alds[wA])       = h0;
            *reinterpret_cast<bf16x8*>(&Alds[wA + 128]) = h1;
        }
        __syncthreads();   // B in LDS, A writes visible

        // issue A(t+1) loads early in compute phase (hidden under ds_read+MFMA)
        if (k0 < 480) {
            p0 = *reinterpret_cast<const float4*>(agp + k0 + 32);
            p1 = *reinterpret_cast<const float4*>(agp + k0 + 36);
            p2 = *reinterpret_cast<const float4*>(agp + k0 + 40);
            p3 = *reinterpret_cast<const float4*>(agp + k0 + 44);
        }

        // ---- compute phase ----
        bf16x8 af[4], bfv[4];
#pragma unroll
        for (int a = 0; a < 4; ++a)
            af[a] = *reinterpret_cast<const bf16x8*>(&Alds[aBase + a * 512]);
#pragma unroll
        for (int b = 0; b < 4; ++b)
            bfv[b] = *reinterpret_cast<const bf16x8*>(&Blds[bBase + b * 512]);
#pragma unroll
        for (int a = 0; a < 4; ++a)
#pragma unroll
            for (int b = 0; b < 4; ++b)
                acc[a][b] = __builtin_amdgcn_mfma_f32_16x16x32_bf16(
                    af[a], bfv[b], acc[a][b], 0, 0, 0);
        __syncthreads();   // compute done before next overwrite
    }

    // ---- epilogue: rsum over this block's 128 cols of tanh(C+b_sa)*w_sc ----
    float rsum[4][4];
#pragma unroll
    for (int a = 0; a < 4; ++a)
#pragma unroll
        for (int r = 0; r < 4; ++r) rsum[a][r] = 0.0f;

#pragma unroll
    for (int b = 0; b < 4; ++b) {
        int col = n0 + wn * 64 + b * 16 + lr;
        float wsc = w_sc[col];
        float bsa = b_sa[col];
#pragma unroll
        for (int a = 0; a < 4; ++a)
#pragma unroll
            for (int r = 0; r < 4; ++r)
                rsum[a][r] += fast_tanhf(acc[a][b][r] + bsa) * wsc;
    }
#pragma unroll
    for (int a = 0; a < 4; ++a)
#pragma unroll
        for (int r = 0; r < 4; ++r) {
            float v = rsum[a][r];
            v += __shfl_xor(v, 1);
            v += __shfl_xor(v, 2);
            v += __shfl_xor(v, 4);
            v += __shfl_xor(v, 8);
            rsum[a][r] = v;
        }
    if (lr == 0) {
#pragma unroll
        for (int a = 0; a < 4; ++a)
#pragma unroll
            for (int r = 0; r < 4; ++r)
                redE[wv][a * 16 + kg * 4 + r] = rsum[a][r];
    }
    __syncthreads();
    if (tid < 128) {
        int wmo = tid >> 6, r64 = tid & 63;
        sp[(size_t)by * 65536 + m0 + tid] = redE[wmo * 2][r64] + redE[wmo * 2 + 1][r64];
    }
}

// ---------------------------------------------------------------------------
// K2: combine 4 partials + b_sc + mask, per-batch masked softmax -> probs
// ---------------------------------------------------------------------------
__global__ void softmax_kernel(const float* __restrict__ sp, const float* __restrict__ b_sc,
                               const int* __restrict__ mask, float* __restrict__ probs) {
    int b = blockIdx.x, t = threadIdx.x;
    int i0 = b * 512 + t, i1 = i0 + 256;
    float s0 = sp[i0] + sp[65536 + i0] + sp[131072 + i0] + sp[196608 + i0] + b_sc[0];
    float s1 = sp[i1] + sp[65536 + i1] + sp[131072 + i1] + sp[196608 + i1] + b_sc[0];
    if (!mask[i0]) s0 = NEG_INF;
    if (!mask[i1]) s1 = NEG_INF;
    float m = fmaxf(s0, s1);
#pragma unroll
    for (int o = 1; o < 64; o <<= 1) m = fmaxf(m, __shfl_xor(m, o));
    __shared__ float red[4];
    if ((t & 63) == 0) red[t >> 6] = m;
    __syncthreads();
    m = fmaxf(fmaxf(red[0], red[1]), fmaxf(red[2], red[3]));
    float e0 = __expf(s0 - m), e1 = __expf(s1 - m);
    float z = e0 + e1;
#pragma unroll
    for (int o = 1; o < 64; o <<= 1) z += __shfl_xor(z, o);
    __syncthreads();
    if ((t & 63) == 0) red[t >> 6] = z;
    __syncthreads();
    float inv = 1.0f / (red[0] + red[1] + red[2] + red[3]);
    probs[i0] = e0 * inv;
    probs[i1] = e1 * inv;
}

// ---------------------------------------------------------------------------
// K3: pooled partial: block (b, c): rows [c*128, c*128+128), float4 cols
// ---------------------------------------------------------------------------
__global__ void pool_kernel(const float* __restrict__ feat,
                            const float* __restrict__ probs,
                            float* __restrict__ part) {
    int b = blockIdx.x, c = blockIdx.y, t = threadIdx.x;
    __shared__ float pl[128];
    __shared__ float red2[2][512];
    if (t < 128) pl[t] = probs[b * 512 + c * 128 + t];
    __syncthreads();
    int col4 = (t & 127) * 4;
    int stripe = t >> 7;
    const float* fb = feat + ((size_t)(b * 512 + c * 128 + stripe * 64)) * 512 + col4;
    float4 a4 = {0.f, 0.f, 0.f, 0.f};
#pragma unroll 8
    for (int n = 0; n < 64; ++n) {
        float p = pl[stripe * 64 + n];
        const float4 f4 = *reinterpret_cast<const float4*>(fb + (size_t)n * 512);
        a4.x = fmaf(p, f4.x, a4.x);
        a4.y = fmaf(p, f4.y, a4.y);
        a4.z = fmaf(p, f4.z, a4.z);
        a4.w = fmaf(p, f4.w, a4.w);
    }
    *reinterpret_cast<float4*>(&red2[stripe][col4]) = a4;
    __syncthreads();
    float x0 = red2[0][t] + red2[1][t];
    float x1 = red2[0][t + 256] + red2[1][t + 256];
    part[(size_t)c * 65536 + b * 512 + t]       = x0;
    part[(size_t)c * 65536 + b * 512 + t + 256] = x1;
}

// ---------------------------------------------------------------------------
// K4: out = tanh(sum of 4 partials)
// ---------------------------------------------------------------------------
__global__ void finish_kernel(const float* __restrict__ part, float* __restrict__ out) {
    int i = blockIdx.x * 256 + threadIdx.x;
    float s = part[i] + part[65536 + i] + part[131072 + i] + part[196608 + i];
    out[i] = fast_tanhf(s);
}

extern "C" void kernel_launch(void* const* d_in, const int* in_sizes, int n_in,
                              void* d_out, int out_size, void* d_ws, size_t ws_size,
                              hipStream_t stream) {
    const float* feat = (const float*)d_in[0];
    const int*   mask = (const int*)d_in[1];
    const float* W_sa = (const float*)d_in[2];
    const float* b_sa = (const float*)d_in[3];
    const float* w_sc = (const float*)d_in[4];
    const float* b_sc = (const float*)d_in[5];
    float* out = (float*)d_out;

    char* ws = (char*)d_ws;
    ushort* Wt    = (ushort*)ws;                               // 512 KB
    float*  sp    = (float*)(ws + (512 << 10));                // 1 MB (4 x 65536)
    float*  probs = (float*)(ws + (512 << 10) + (1024 << 10)); // 256 KB
    float*  part  = (float*)(ws + (512 << 10) + (1280 << 10)); // 1 MB (4 x 65536)

    hipLaunchKernelGGL(convw_kernel, dim3(1024), dim3(256), 0, stream, W_sa, Wt);
    hipLaunchKernelGGL(gemm_scores_kernel, dim3(2048), dim3(256), 0, stream,
                       feat, Wt, b_sa, w_sc, sp);
    hipLaunchKernelGGL(softmax_kernel, dim3(128), dim3(256), 0, stream,
                       sp, b_sc, mask, probs);
    hipLaunchKernelGGL(pool_kernel, dim3(128, 4), dim3(256), 0, stream, feat, probs, part);
    hipLaunchKernelGGL(finish_kernel, dim3(256), dim3(256), 0, stream, part, out);
}

// Round 7
// 114.279 us; speedup vs baseline: 1.5186x; 1.5186x over previous
//
#include <hip/hip_runtime.h>

#define NEG_INF (-1e30f)

typedef __bf16 bf16x8 __attribute__((ext_vector_type(8)));
typedef float  f32x4  __attribute__((ext_vector_type(4)));
typedef unsigned short ushort;

__device__ __forceinline__ float fast_tanhf(float x) {
    // 1 - 2*rcp(1+e^{2x}) : v_exp + v_rcp, no IEEE divide (validated in R6)
    float e = __expf(2.0f * x);
    return 1.0f - 2.0f * __builtin_amdgcn_rcpf(1.0f + e);
}

__device__ __forceinline__ ushort f2bf(float f) {
    union { float f; unsigned u; } v; v.f = f;
    unsigned r = v.u + 0x7fffu + ((v.u >> 16) & 1u);   // RNE
    return (ushort)(r >> 16);
}

// async global->LDS, 16B/lane, LDS dest = wave-uniform base + lane*16
__device__ __forceinline__ void gload_lds16(const void* gsrc, void* ldsdst) {
    __builtin_amdgcn_global_load_lds(
        (const __attribute__((address_space(1))) unsigned int*)gsrc,
        (__attribute__((address_space(3))) unsigned int*)ldsdst, 16, 0, 0);
}

// ---------------------------------------------------------------------------
// K0: W_sa [H=512][C=512] fp32 -> Wt [C][H] bf16 (transposed)
// ---------------------------------------------------------------------------
__global__ void convw_kernel(const float* __restrict__ W, ushort* __restrict__ Wt) {
    int i = blockIdx.x * 256 + threadIdx.x;
    int h = i >> 9, c = i & 511;
    Wt[c * 512 + h] = f2bf(W[i]);
}

// ---------------------------------------------------------------------------
// K1: B-resident GEMM. 512 thr / 8 waves. Block owns (256 M-rows) x (128 cols).
// B panel half (128 cols x 256 K, bf16) = 64 KB LDS, loaded once per pass via
// glds; then an 8-K-step loop with ZERO barriers: each wave streams its own
// 32 A-rows fp32->bf16 from global and MFMAs against resident B.
// LDS layout: ushort idx = kl*4096 + cf*512 + kg*128 + lr*8
//   -> frag ds_read_b128: 64 lanes read 1024 contiguous bytes (conflict-free).
// Grid 1024, XCD-packed: g=id&7 -> msuper g*32+(loc>>2), by=loc&3, so the 4
// by-sharers of an M-super are co-resident on one XCD's L2.
// ---------------------------------------------------------------------------
__global__ __launch_bounds__(512) void gemm_scores_kernel(
    const float* __restrict__ feat, const ushort* __restrict__ Wt,
    const float* __restrict__ b_sa, const float* __restrict__ w_sc,
    float* __restrict__ sp) {

    __shared__ ushort Blds[32768];   // 64 KB: [kl 8][cf 8][kg 4][lr 16][8]

    const int tid  = threadIdx.x;
    const int wv   = tid >> 6;
    const int lane = tid & 63;
    const int lr   = lane & 15;
    const int kg   = lane >> 4;

    const int id   = blockIdx.x;
    const int g    = id & 7;
    const int loc  = id >> 3;
    const int msuper = g * 32 + (loc >> 2);   // 0..255
    const int by   = loc & 3;                 // 0..3
    const int m0   = msuper * 256;
    const int n0   = by * 128;
    const int mw   = m0 + wv * 32;            // this wave's 32 rows

    const float*  ag0  = feat + (size_t)(mw + lr) * 512 + kg * 8;   // grp0 rows
    const float*  ag1  = ag0 + 16 * 512;                             // grp1 rows
    const ushort* bsrc = Wt + (size_t)(n0 + wv * 16 + lr) * 512 + kg * 8;

    f32x4 acc[2][8];
#pragma unroll
    for (int gr = 0; gr < 2; ++gr)
#pragma unroll
        for (int cf = 0; cf < 8; ++cf) acc[gr][cf] = (f32x4){0.f, 0.f, 0.f, 0.f};

    for (int pass = 0; pass < 2; ++pass) {
        if (pass) __syncthreads();   // all waves done reading Blds (lgkm drained)
        // load this pass's B half: 8 glds rounds; wave wv = col-frag cf=wv,
        // round r = local k-step kl=r; dest linear chunk r*8192 + wv*1024 bytes.
#pragma unroll
        for (int r = 0; r < 8; ++r)
            gload_lds16(bsrc + pass * 256 + r * 32,
                        (char*)Blds + r * 8192 + wv * 1024);
        __syncthreads();             // drains vmcnt(0): B resident

        // ---- barrier-free K loop: 8 steps ----
#pragma unroll
        for (int kl = 0; kl < 8; ++kl) {
            const int kgl = pass * 256 + kl * 32;
            const float4 q0 = *reinterpret_cast<const float4*>(ag0 + kgl);
            const float4 q1 = *reinterpret_cast<const float4*>(ag0 + kgl + 4);
            const float4 q2 = *reinterpret_cast<const float4*>(ag1 + kgl);
            const float4 q3 = *reinterpret_cast<const float4*>(ag1 + kgl + 4);
            bf16x8 a0, a1;
            a0[0] = (__bf16)q0.x; a0[1] = (__bf16)q0.y; a0[2] = (__bf16)q0.z; a0[3] = (__bf16)q0.w;
            a0[4] = (__bf16)q1.x; a0[5] = (__bf16)q1.y; a0[6] = (__bf16)q1.z; a0[7] = (__bf16)q1.w;
            a1[0] = (__bf16)q2.x; a1[1] = (__bf16)q2.y; a1[2] = (__bf16)q2.z; a1[3] = (__bf16)q2.w;
            a1[4] = (__bf16)q3.x; a1[5] = (__bf16)q3.y; a1[6] = (__bf16)q3.z; a1[7] = (__bf16)q3.w;
#pragma unroll
            for (int cf = 0; cf < 8; ++cf) {
                const bf16x8 bf = *reinterpret_cast<const bf16x8*>(
                    (const char*)Blds + kl * 8192 + cf * 1024 + kg * 256 + lr * 16);
                acc[0][cf] = __builtin_amdgcn_mfma_f32_16x16x32_bf16(a0, bf, acc[0][cf], 0, 0, 0);
                acc[1][cf] = __builtin_amdgcn_mfma_f32_16x16x32_bf16(a1, bf, acc[1][cf], 0, 0, 0);
            }
        }
    }

    // ---- wave-local epilogue: rsum over 128 cols of tanh(C+b_sa)*w_sc ----
    float rs[2][4];
#pragma unroll
    for (int gr = 0; gr < 2; ++gr)
#pragma unroll
        for (int r = 0; r < 4; ++r) rs[gr][r] = 0.0f;

#pragma unroll
    for (int cf = 0; cf < 8; ++cf) {
        const int col = n0 + cf * 16 + lr;
        const float w = w_sc[col];
        const float b = b_sa[col];
#pragma unroll
        for (int gr = 0; gr < 2; ++gr)
#pragma unroll
            for (int r = 0; r < 4; ++r)
                rs[gr][r] += fast_tanhf(acc[gr][cf][r] + b) * w;
    }
#pragma unroll
    for (int gr = 0; gr < 2; ++gr)
#pragma unroll
        for (int r = 0; r < 4; ++r) {
            float v = rs[gr][r];
            v += __shfl_xor(v, 1);
            v += __shfl_xor(v, 2);
            v += __shfl_xor(v, 4);
            v += __shfl_xor(v, 8);
            rs[gr][r] = v;
        }
    if (lr == 0) {
        // row = mw + gr*16 + kg*4 + r
#pragma unroll
        for (int gr = 0; gr < 2; ++gr)
#pragma unroll
            for (int r = 0; r < 4; ++r)
                sp[(size_t)by * 65536 + mw + gr * 16 + kg * 4 + r] = rs[gr][r];
    }
}

// ---------------------------------------------------------------------------
// K2: combine 4 partials + b_sc + mask, per-batch masked softmax -> probs
// ---------------------------------------------------------------------------
__global__ void softmax_kernel(const float* __restrict__ sp, const float* __restrict__ b_sc,
                               const int* __restrict__ mask, float* __restrict__ probs) {
    int b = blockIdx.x, t = threadIdx.x;
    int i0 = b * 512 + t, i1 = i0 + 256;
    float s0 = sp[i0] + sp[65536 + i0] + sp[131072 + i0] + sp[196608 + i0] + b_sc[0];
    float s1 = sp[i1] + sp[65536 + i1] + sp[131072 + i1] + sp[196608 + i1] + b_sc[0];
    if (!mask[i0]) s0 = NEG_INF;
    if (!mask[i1]) s1 = NEG_INF;
    float m = fmaxf(s0, s1);
#pragma unroll
    for (int o = 1; o < 64; o <<= 1) m = fmaxf(m, __shfl_xor(m, o));
    __shared__ float red[4];
    if ((t & 63) == 0) red[t >> 6] = m;
    __syncthreads();
    m = fmaxf(fmaxf(red[0], red[1]), fmaxf(red[2], red[3]));
    float e0 = __expf(s0 - m), e1 = __expf(s1 - m);
    float z = e0 + e1;
#pragma unroll
    for (int o = 1; o < 64; o <<= 1) z += __shfl_xor(z, o);
    __syncthreads();
    if ((t & 63) == 0) red[t >> 6] = z;
    __syncthreads();
    float inv = 1.0f / (red[0] + red[1] + red[2] + red[3]);
    probs[i0] = e0 * inv;
    probs[i1] = e1 * inv;
}

// ---------------------------------------------------------------------------
// K3: pooled partial: block (b, c): rows [c*128, c*128+128), float4 cols
// ---------------------------------------------------------------------------
__global__ void pool_kernel(const float* __restrict__ feat,
                            const float* __restrict__ probs,
                            float* __restrict__ part) {
    int b = blockIdx.x, c = blockIdx.y, t = threadIdx.x;
    __shared__ float pl[128];
    __shared__ float red2[2][512];
    if (t < 128) pl[t] = probs[b * 512 + c * 128 + t];
    __syncthreads();
    int col4 = (t & 127) * 4;
    int stripe = t >> 7;
    const float* fb = feat + ((size_t)(b * 512 + c * 128 + stripe * 64)) * 512 + col4;
    float4 a4 = {0.f, 0.f, 0.f, 0.f};
#pragma unroll 8
    for (int n = 0; n < 64; ++n) {
        float p = pl[stripe * 64 + n];
        const float4 f4 = *reinterpret_cast<const float4*>(fb + (size_t)n * 512);
        a4.x = fmaf(p, f4.x, a4.x);
        a4.y = fmaf(p, f4.y, a4.y);
        a4.z = fmaf(p, f4.z, a4.z);
        a4.w = fmaf(p, f4.w, a4.w);
    }
    *reinterpret_cast<float4*>(&red2[stripe][col4]) = a4;
    __syncthreads();
    float x0 = red2[0][t] + red2[1][t];
    float x1 = red2[0][t + 256] + red2[1][t + 256];
    part[(size_t)c * 65536 + b * 512 + t]       = x0;
    part[(size_t)c * 65536 + b * 512 + t + 256] = x1;
}

// ---------------------------------------------------------------------------
// K4: out = tanh(sum of 4 partials)
// ---------------------------------------------------------------------------
__global__ void finish_kernel(const float* __restrict__ part, float* __restrict__ out) {
    int i = blockIdx.x * 256 + threadIdx.x;
    float s = part[i] + part[65536 + i] + part[131072 + i] + part[196608 + i];
    out[i] = fast_tanhf(s);
}

extern "C" void kernel_launch(void* const* d_in, const int* in_sizes, int n_in,
                              void* d_out, int out_size, void* d_ws, size_t ws_size,
                              hipStream_t stream) {
    const float* feat = (const float*)d_in[0];
    const int*   mask = (const int*)d_in[1];
    const float* W_sa = (const float*)d_in[2];
    const float* b_sa = (const float*)d_in[3];
    const float* w_sc = (const float*)d_in[4];
    const float* b_sc = (const float*)d_in[5];
    float* out = (float*)d_out;

    char* ws = (char*)d_ws;
    ushort* Wt    = (ushort*)ws;                               // 512 KB
    float*  sp    = (float*)(ws + (512 << 10));                // 1 MB (4 x 65536)
    float*  probs = (float*)(ws + (512 << 10) + (1024 << 10)); // 256 KB
    float*  part  = (float*)(ws + (512 << 10) + (1280 << 10)); // 1 MB (4 x 65536)

    hipLaunchKernelGGL(convw_kernel, dim3(1024), dim3(256), 0, stream, W_sa, Wt);
    hipLaunchKernelGGL(gemm_scores_kernel, dim3(1024), dim3(512), 0, stream,
                       feat, Wt, b_sa, w_sc, sp);
    hipLaunchKernelGGL(softmax_kernel, dim3(128), dim3(256), 0, stream,
                       sp, b_sc, mask, probs);
    hipLaunchKernelGGL(pool_kernel, dim3(128, 4), dim3(256), 0, stream, feat, probs, part);
    hipLaunchKernelGGL(finish_kernel, dim3(256), dim3(256), 0, stream, part, out);
}